// Round 7
// baseline (135.632 us; speedup 1.0000x reference)
//
#include <hip/hip_runtime.h>
#include <hip/hip_fp16.h>
#include <math.h>
#include <string.h>

#define ATOM_VOC 128
#define APO      128
#define NHEAD    16
#define D_MODEL  512
#define NB       4
#define NL       384

typedef __attribute__((ext_vector_type(8))) _Float16 f16x8;
typedef __attribute__((ext_vector_type(4))) float    f32x4;
typedef __attribute__((ext_vector_type(4))) unsigned u32x4;

#define PACK_DWORDS (ATOM_VOC * ATOM_VOC * APO)   // 2M dwords = 8 MB
#define BFT_SHORTS  (4 * 4 * 16 * 8)              // 2048 f16 = 4 KB

static __device__ inline unsigned short f2h(float x) {
    __half h = __float2half(x);
    unsigned short u; memcpy(&u, &h, 2); return u;
}

// ---------------------------------------------------------------------------
// Kernel 0: packed fp16 table, row layout per (ai, v): 128 dwords =
//   [64 w-pair dwords | 64 b-pair dwords], pair p = (k=2p, k=2p+1),
//   w' = w*ag, b' = (b-mean)*ag, ag = sqrt(log2e)/(sqrt(2)*s).
// Then gauss = exp2(-u^2) with u = pk_fma(w', dist, b').
// Block (0,0) also builds the f16 B-fragment table bft[cid=(ks*4+quad)*16+h][8]
// = lin_w[h][k]*z, z = 1/(sqrt(2pi)s) (so MFMA output needs no extra scale).
// ---------------------------------------------------------------------------
__global__ __launch_bounds__(128) void pack_kernel(
    const float* __restrict__ apw, const float* __restrict__ apb,
    const float* __restrict__ means, const float* __restrict__ stds,
    const float* __restrict__ lin_w,
    unsigned* __restrict__ pack, unsigned short* __restrict__ bft, int write_bft)
{
    const int t    = threadIdx.x;   // 0..127
    const int v    = blockIdx.x;    // aj value
    const int ai   = blockIdx.y;    // ai value
    const int half = t >> 6;        // 0 = w-pairs, 1 = b-pairs
    const int p    = t & 63;
    const int k0   = 2 * p, k1 = 2 * p + 1;

    const float s0  = fabsf(stds[k0]) + 1e-5f;
    const float s1  = fabsf(stds[k1]) + 1e-5f;
    const float ag0 = 0.84932180028802f / s0;   // sqrt(log2e)/sqrt(2)/s
    const float ag1 = 0.84932180028802f / s1;

    const size_t srcrow = ((size_t)v * ATOM_VOC + ai) * APO;
    float x0, x1;
    if (half == 0) {
        x0 = apw[srcrow + k0] * ag0;
        x1 = apw[srcrow + k1] * ag1;
    } else {
        x0 = (apb[srcrow + k0] - means[k0]) * ag0;
        x1 = (apb[srcrow + k1] - means[k1]) * ag1;
    }
    pack[((size_t)ai * ATOM_VOC + v) * APO + half * 64 + p] =
        ((unsigned)f2h(x1) << 16) | f2h(x0);

    if (write_bft && v == 0 && ai == 0) {
#pragma unroll
        for (int hh = 0; hh < 2; ++hh) {
            const int cid  = t + hh * 128;
            const int ks   = cid >> 6;
            const int quad = (cid >> 4) & 3;
            const int h    = cid & 15;
            const int kb   = ks * 32 + quad * 8;
            unsigned short tmp[8];
#pragma unroll
            for (int u = 0; u < 8; ++u) {
                const int kk = kb + u;
                float z = 0.3989422804014327f / (fabsf(stds[kk]) + 1e-5f);
                tmp[u] = f2h(lin_w[h * APO + kk] * z);
            }
            memcpy(&bft[(size_t)cid * 8], tmp, 16);
        }
    }
}

// ---------------------------------------------------------------------------
// Kernel 1: atoms_emb[l, b, d] = atype_emb[atoms[b,l]] + chiral_emb[chirals[b,l]]
// ---------------------------------------------------------------------------
__global__ __launch_bounds__(256) void atoms_emb_kernel(
    const int* __restrict__ atoms, const int* __restrict__ chirals,
    const float* __restrict__ atype_emb, const float* __restrict__ chiral_emb,
    float* __restrict__ out)
{
    const int D4 = D_MODEL / 4;
    int t = blockIdx.x * 256 + threadIdx.x;
    if (t >= NL * NB * D4) return;
    int d4 = t % D4;
    int bl = t / D4;          // = l*NB + b
    int b  = bl % NB;
    int l  = bl / NB;
    int a  = atoms[b * NL + l];
    int c  = chirals[b * NL + l];
    float4 va = ((const float4*)(atype_emb  + (size_t)a * D_MODEL))[d4];
    float4 vc = ((const float4*)(chiral_emb + (size_t)c * D_MODEL))[d4];
    float4 o;
    o.x = va.x + vc.x; o.y = va.y + vc.y; o.z = va.z + vc.z; o.w = va.w + vc.w;
    ((float4*)out)[t] = o;
}

// ---------------------------------------------------------------------------
// Kernel 2: ap[b,h,i,j]. One block (512 thr, 8 waves) per (b,i).
// fp16 packed gaussians straight into mfma_f32_16x16x32_f16 A-fragments;
// 2-stage pipeline of LDS reads + epilogue index loads across j-iters.
// LDS row (512 B) per v: [w-half | b-half], 16B chunks XOR-swizzled by v&15.
// ---------------------------------------------------------------------------
__global__ __launch_bounds__(512, 4) void ap_kernel(
    const int*            __restrict__ atoms,
    const float*          __restrict__ coords,
    const int*            __restrict__ bonds,
    const unsigned*       __restrict__ pack,
    const unsigned short* __restrict__ bft,
    const float*          __restrict__ bond_emb,
    const float*          __restrict__ lin_b,
    float*                __restrict__ out)
{
    const int i    = blockIdx.x;
    const int b    = blockIdx.y;
    const int t    = threadIdx.x;
    const int lane = t & 63;
    const int wave = t >> 6;
    const int h    = lane & 15;
    const int quad = lane >> 4;

    __shared__ unsigned tbl[ATOM_VOC * APO];   // 64 KB

    const int ai = atoms[b * NL + i];

    // ---- stage packed slice for this ai: coalesced, XOR-swizzled ----
    const unsigned* src = pack + (size_t)ai * (ATOM_VOC * APO);
#pragma unroll
    for (int it = 0; it < 8; ++it) {
        int c    = it * 512 + t;    // 16B-chunk id, 0..4095
        int v    = c >> 5;          // 32 chunks per 512B row
        int cc   = c & 31;
        int hlf  = cc >> 4;
        int cp   = cc & 15;
        u32x4 d  = ((const u32x4*)src)[c];
        *(u32x4*)&tbl[v * APO + hlf * 64 + 4 * (cp ^ (v & 15))] = d;
    }

    // ---- B fragments from precomputed table (coalesced b128) ----
    f16x8 bfrag[4];
#pragma unroll
    for (int ks = 0; ks < 4; ++ks)
        memcpy(&bfrag[ks], bft + ((size_t)((ks * 4 + quad) * 16 + h)) * 8, 16);
    const float lbh = lin_b[h];

    const float cix = coords[((size_t)b * NL + i) * 3 + 0];
    const float ciy = coords[((size_t)b * NL + i) * 3 + 1];
    const float ciz = coords[((size_t)b * NL + i) * 3 + 2];

    // ---- per-iteration j metadata (3 iters) ----
    int     jv[3];
    __half2 jd2[3];
#pragma unroll
    for (int it = 0; it < 3; ++it) {
        const int j = it * 128 + wave * 16 + h;
        jv[it] = atoms[b * NL + j];
        const float dx = coords[((size_t)b * NL + j) * 3 + 0] - cix;
        const float dy = coords[((size_t)b * NL + j) * 3 + 1] - ciy;
        const float dz = coords[((size_t)b * NL + j) * 3 + 2] - ciz;
        jd2[it] = __half2half2(__float2half(
            sqrtf(fmaf(dx, dx, fmaf(dy, dy, dz * dz)) + 1e-12f)));
    }

    __syncthreads();

    const size_t bondrow = ((size_t)b * NL + i) * NL;
    float* op = out + (((size_t)(b * NHEAD + h)) * NL + i) * NL;

    // pipeline registers
    u32x4 pa[2][8];
    int   bidx[2][4], aje[2][4];

    // issue stage for iteration `it` into slot s
#define ISSUE(itc, s)                                                         \
    {                                                                         \
        const int v_    = jv[itc];                                            \
        const int vb_   = v_ * APO;                                           \
        const int vx_   = v_ & 15;                                            \
        _Pragma("unroll")                                                     \
        for (int cc = 0; cc < 8; ++cc) {                                      \
            const int ks_ = cc >> 1, e_ = cc & 1;                             \
            pa[s][cc] = *(const u32x4*)&tbl[vb_ + e_ * 64 +                   \
                                           4 * ((ks_ * 4 + quad) ^ vx_)];     \
        }                                                                     \
        const int jb_ = itc * 128 + wave * 16 + quad * 4;                     \
        _Pragma("unroll")                                                     \
        for (int r = 0; r < 4; ++r) {                                         \
            bidx[s][r] = bonds[bondrow + jb_ + r];                            \
            aje[s][r]  = atoms[b * NL + jb_ + r];                             \
        }                                                                     \
    }

    ISSUE(0, 0)

#pragma unroll
    for (int it = 0; it < 3; ++it) {
        const int s = it & 1;
        if (it < 2) ISSUE(it + 1, (it + 1) & 1)

        const __half2 d2 = jd2[it];
        f32x4 acc = {0.f, 0.f, 0.f, 0.f};
#pragma unroll
        for (int ks = 0; ks < 4; ++ks) {
            const u32x4 wch = pa[s][ks * 2 + 0];
            const u32x4 bch = pa[s][ks * 2 + 1];
            unsigned afw[4];
#pragma unroll
            for (int q = 0; q < 4; ++q) {
                __half2 w2, b2;
                unsigned wd = wch[q], bd = bch[q];   // ext-vector subscript
                memcpy(&w2, &wd, 4); memcpy(&b2, &bd, 4);
                __half2 u2  = __hfma2(w2, d2, b2);
                __half2 nm2 = __hmul2(u2, __hneg2(u2));   // -u^2
                __half2 g2  = h2exp2(nm2);                // exp2(-u^2)
                memcpy(&afw[q], &g2, 4);
            }
            f16x8 af;
            memcpy(&af, afw, 16);
            acc = __builtin_amdgcn_mfma_f32_16x16x32_f16(af, bfrag[ks], acc, 0, 0, 0);
        }

        // ---- epilogue: C row = quad*4+r, col = h ----
        const int jb = it * 128 + wave * 16 + quad * 4;
#pragma unroll
        for (int r = 0; r < 4; ++r) {
            float vv = acc[r] + lbh + bond_emb[bidx[s][r] * NHEAD + h];
            if (aje[s][r] == 0) vv = -1.0e30f;   // finite -inf sentinel
            op[jb + r] = vv;
        }
    }
#undef ISSUE
}

extern "C" void kernel_launch(void* const* d_in, const int* in_sizes, int n_in,
                              void* d_out, int out_size, void* d_ws, size_t ws_size,
                              hipStream_t stream)
{
    const int*   atoms      = (const int*)d_in[0];
    const int*   chirals    = (const int*)d_in[1];
    const float* coords     = (const float*)d_in[2];
    const int*   bonds      = (const int*)d_in[3];
    const float* atype_emb  = (const float*)d_in[4];
    const float* chiral_emb = (const float*)d_in[5];
    const float* apw        = (const float*)d_in[6];
    const float* apb        = (const float*)d_in[7];
    const float* means      = (const float*)d_in[8];
    const float* stds       = (const float*)d_in[9];
    const float* bond_emb   = (const float*)d_in[10];
    const float* lin_w      = (const float*)d_in[11];
    const float* lin_b      = (const float*)d_in[12];
    float* out = (float*)d_out;

    unsigned* pack = (unsigned*)d_ws;                      // 8 MB
    unsigned short* bftp = (unsigned short*)((char*)d_ws + (size_t)PACK_DWORDS * 4);

    // Kernel 0: repack tables (+ B-fragment table); ws re-poisoned each call
    pack_kernel<<<dim3(ATOM_VOC, ATOM_VOC), dim3(128), 0, stream>>>(
        apw, apb, means, stds, lin_w, pack, bftp, 1);

    // Output 1: atoms_emb [L, B, D] at offset 0
    {
        const int total = NL * NB * (D_MODEL / 4);
        atoms_emb_kernel<<<dim3((total + 255) / 256), dim3(256), 0, stream>>>(
            atoms, chirals, atype_emb, chiral_emb, out);
    }
    // Output 2: ap [B, NHEAD, L, L] at offset L*B*D
    {
        float* out2 = out + (size_t)NL * NB * D_MODEL;
        ap_kernel<<<dim3(NL, NB), dim3(512), 0, stream>>>(
            atoms, coords, bonds, pack, bftp, bond_emb, lin_b, out2);
    }
}

// Round 8
// 131.443 us; speedup vs baseline: 1.0319x; 1.0319x over previous
//
#include <hip/hip_runtime.h>
#include <hip/hip_fp16.h>
#include <math.h>
#include <string.h>

#define ATOM_VOC 128
#define APO      128
#define NHEAD    16
#define D_MODEL  512
#define NB       4
#define NL       384

typedef __attribute__((ext_vector_type(8))) _Float16 f16x8;
typedef __attribute__((ext_vector_type(4))) float    f32x4;
typedef __attribute__((ext_vector_type(4))) unsigned u32x4;

#define PACK_DWORDS (ATOM_VOC * ATOM_VOC * APO)   // 2M dwords = 8 MB
#define BFT_SHORTS  (4 * 4 * 16 * 8)              // 2048 f16 = 4 KB

static __device__ inline unsigned short f2h(float x) {
    __half h = __float2half(x);
    unsigned short u; memcpy(&u, &h, 2); return u;
}

// ---------------------------------------------------------------------------
// Kernel 0: packed fp16 table. Row (128 dwords = 512 B) per (ai, v), layout:
//   [phase0: 32 w-pair dw | 32 b-pair dw][phase1: 32 w-pair dw | 32 b-pair dw]
// pair p = (k=2p, k=2p+1); phase = p>>5 (k<64 / k>=64).
//   w' = w*ag, b' = (b-mean)*ag, ag = sqrt(log2e)/(sqrt(2)*s);
//   gauss = exp2(-u^2), u = pk_fma(w', dist, b').
// Block (0,0) also builds f16 B-fragment table bft[(ks*4+quad)*16+h][8]
//   = lin_w[h][k] * 1/(sqrt(2pi)s).
// ---------------------------------------------------------------------------
__global__ __launch_bounds__(128) void pack_kernel(
    const float* __restrict__ apw, const float* __restrict__ apb,
    const float* __restrict__ means, const float* __restrict__ stds,
    const float* __restrict__ lin_w,
    unsigned* __restrict__ pack, unsigned short* __restrict__ bft, int write_bft)
{
    const int t    = threadIdx.x;   // 0..127
    const int v    = blockIdx.x;    // aj value
    const int ai   = blockIdx.y;    // ai value
    const int half = t >> 6;        // 0 = w-pairs, 1 = b-pairs
    const int p    = t & 63;        // pair index 0..63
    const int k0   = 2 * p, k1 = 2 * p + 1;

    const float s0  = fabsf(stds[k0]) + 1e-5f;
    const float s1  = fabsf(stds[k1]) + 1e-5f;
    const float ag0 = 0.84932180028802f / s0;   // sqrt(log2e)/sqrt(2)/s
    const float ag1 = 0.84932180028802f / s1;

    const size_t srcrow = ((size_t)v * ATOM_VOC + ai) * APO;
    float x0, x1;
    if (half == 0) {
        x0 = apw[srcrow + k0] * ag0;
        x1 = apw[srcrow + k1] * ag1;
    } else {
        x0 = (apb[srcrow + k0] - means[k0]) * ag0;
        x1 = (apb[srcrow + k1] - means[k1]) * ag1;
    }
    const int dst = (p >> 5) * 64 + half * 32 + (p & 31);
    pack[((size_t)ai * ATOM_VOC + v) * APO + dst] =
        ((unsigned)f2h(x1) << 16) | f2h(x0);

    if (write_bft && v == 0 && ai == 0) {
#pragma unroll
        for (int hh = 0; hh < 2; ++hh) {
            const int cid  = t + hh * 128;
            const int ks   = cid >> 6;
            const int quad = (cid >> 4) & 3;
            const int h    = cid & 15;
            const int kb   = ks * 32 + quad * 8;
            unsigned short tmp[8];
#pragma unroll
            for (int u = 0; u < 8; ++u) {
                const int kk = kb + u;
                float z = 0.3989422804014327f / (fabsf(stds[kk]) + 1e-5f);
                tmp[u] = f2h(lin_w[h * APO + kk] * z);
            }
            memcpy(&bft[(size_t)cid * 8], tmp, 16);
        }
    }
}

// ---------------------------------------------------------------------------
// Kernel 1: atoms_emb[l, b, d] = atype_emb[atoms[b,l]] + chiral_emb[chirals[b,l]]
// ---------------------------------------------------------------------------
__global__ __launch_bounds__(256) void atoms_emb_kernel(
    const int* __restrict__ atoms, const int* __restrict__ chirals,
    const float* __restrict__ atype_emb, const float* __restrict__ chiral_emb,
    float* __restrict__ out)
{
    const int D4 = D_MODEL / 4;
    int t = blockIdx.x * 256 + threadIdx.x;
    if (t >= NL * NB * D4) return;
    int d4 = t % D4;
    int bl = t / D4;          // = l*NB + b
    int b  = bl % NB;
    int l  = bl / NB;
    int a  = atoms[b * NL + l];
    int c  = chirals[b * NL + l];
    float4 va = ((const float4*)(atype_emb  + (size_t)a * D_MODEL))[d4];
    float4 vc = ((const float4*)(chiral_emb + (size_t)c * D_MODEL))[d4];
    float4 o;
    o.x = va.x + vc.x; o.y = va.y + vc.y; o.z = va.z + vc.z; o.w = va.w + vc.w;
    ((float4*)out)[t] = o;
}

// ---------------------------------------------------------------------------
// Kernel 2: ap[b,h,i,j]. One block (512 thr, 8 waves) per (b,i).
// Two k-phases of 64: stage 32 KB table slice per phase (halves LDS ->
// 4 blocks/CU = 32 waves/CU, 2x occupancy vs the 64 KB version).
// acc for all 3 j-iterations carried across phases; epilogue after phase 1.
// LDS row (256 B) per v per phase: [8 w-chunks | 8 b-chunks] of 16 B,
// chunk index XOR-swizzled by v&15.
// ---------------------------------------------------------------------------
__global__ __launch_bounds__(512, 8) void ap_kernel(
    const int*            __restrict__ atoms,
    const float*          __restrict__ coords,
    const int*            __restrict__ bonds,
    const unsigned*       __restrict__ pack,
    const unsigned short* __restrict__ bft,
    const float*          __restrict__ bond_emb,
    const float*          __restrict__ lin_b,
    float*                __restrict__ out)
{
    const int i    = blockIdx.x;
    const int b    = blockIdx.y;
    const int t    = threadIdx.x;
    const int lane = t & 63;
    const int wave = t >> 6;
    const int h    = lane & 15;
    const int quad = lane >> 4;

    __shared__ unsigned tbl[ATOM_VOC * 64];   // 32 KB: one phase's slice

    const int ai = atoms[b * NL + i];
    const unsigned* src = pack + (size_t)ai * (ATOM_VOC * APO);

    // ---- B fragments from precomputed table (coalesced b128) ----
    f16x8 bfrag[4];
#pragma unroll
    for (int ks = 0; ks < 4; ++ks)
        memcpy(&bfrag[ks], bft + ((size_t)((ks * 4 + quad) * 16 + h)) * 8, 16);
    const float lbh = lin_b[h];

    const float cix = coords[((size_t)b * NL + i) * 3 + 0];
    const float ciy = coords[((size_t)b * NL + i) * 3 + 1];
    const float ciz = coords[((size_t)b * NL + i) * 3 + 2];

    // ---- per-iteration j metadata (3 iters) ----
    int     jv[3];
    __half2 jd2[3];
#pragma unroll
    for (int it = 0; it < 3; ++it) {
        const int j = it * 128 + wave * 16 + h;
        jv[it] = atoms[b * NL + j];
        const float dx = coords[((size_t)b * NL + j) * 3 + 0] - cix;
        const float dy = coords[((size_t)b * NL + j) * 3 + 1] - ciy;
        const float dz = coords[((size_t)b * NL + j) * 3 + 2] - ciz;
        jd2[it] = __half2half2(__float2half(
            sqrtf(fmaf(dx, dx, fmaf(dy, dy, dz * dz)) + 1e-12f)));
    }

    f32x4 acc[3] = {{0.f,0.f,0.f,0.f},{0.f,0.f,0.f,0.f},{0.f,0.f,0.f,0.f}};

#pragma unroll
    for (int ph = 0; ph < 2; ++ph) {
        // ---- stage this phase's 32 KB slice: coalesced, XOR-swizzled ----
        if (ph) __syncthreads();   // drain phase-0 readers before overwrite
#pragma unroll
        for (int itx = 0; itx < 4; ++itx) {
            int c   = itx * 512 + t;       // 16B-chunk id, 0..2047
            int row = c >> 4;              // v
            int cc  = c & 15;              // chunk within phase row
            u32x4 d = ((const u32x4*)src)[row * 32 + ph * 16 + cc];
            *(u32x4*)&tbl[row * 64 + 4 * (cc ^ (row & 15))] = d;
        }
        __syncthreads();

#pragma unroll
        for (int it = 0; it < 3; ++it) {
            const int v  = jv[it];
            const int vb = v * 64;
            const int vx = v & 15;
            const __half2 d2 = jd2[it];
#pragma unroll
            for (int ks2 = 0; ks2 < 2; ++ks2) {
                const u32x4 wch = *(const u32x4*)&tbl[vb + 4 * ((ks2 * 4 + quad) ^ vx)];
                const u32x4 bch = *(const u32x4*)&tbl[vb + 4 * ((8 + ks2 * 4 + quad) ^ vx)];
                unsigned afw[4];
#pragma unroll
                for (int q = 0; q < 4; ++q) {
                    __half2 w2, b2;
                    unsigned wd = wch[q], bd = bch[q];
                    memcpy(&w2, &wd, 4); memcpy(&b2, &bd, 4);
                    __half2 u2  = __hfma2(w2, d2, b2);
                    __half2 nm2 = __hmul2(u2, __hneg2(u2));   // -u^2 (pk_mul w/ neg)
                    __half2 g2  = h2exp2(nm2);                // exp2(-u^2)
                    memcpy(&afw[q], &g2, 4);
                }
                f16x8 af;
                memcpy(&af, afw, 16);
                acc[it] = __builtin_amdgcn_mfma_f32_16x16x32_f16(
                    af, bfrag[ph * 2 + ks2], acc[it], 0, 0, 0);
            }
        }
    }

    // ---- epilogue: C row = quad*4+r, col = h ----
    const size_t bondrow = ((size_t)b * NL + i) * NL;
    float* op = out + (((size_t)(b * NHEAD + h)) * NL + i) * NL;
#pragma unroll
    for (int it = 0; it < 3; ++it) {
        const int jb = it * 128 + wave * 16 + quad * 4;
#pragma unroll
        for (int r = 0; r < 4; ++r) {
            const int bidx = bonds[bondrow + jb + r];
            const int ajr  = atoms[b * NL + jb + r];
            float vv = acc[it][r] + lbh + bond_emb[bidx * NHEAD + h];
            if (ajr == 0) vv = -1.0e30f;   // finite -inf sentinel
            op[jb + r] = vv;
        }
    }
}

extern "C" void kernel_launch(void* const* d_in, const int* in_sizes, int n_in,
                              void* d_out, int out_size, void* d_ws, size_t ws_size,
                              hipStream_t stream)
{
    const int*   atoms      = (const int*)d_in[0];
    const int*   chirals    = (const int*)d_in[1];
    const float* coords     = (const float*)d_in[2];
    const int*   bonds      = (const int*)d_in[3];
    const float* atype_emb  = (const float*)d_in[4];
    const float* chiral_emb = (const float*)d_in[5];
    const float* apw        = (const float*)d_in[6];
    const float* apb        = (const float*)d_in[7];
    const float* means      = (const float*)d_in[8];
    const float* stds       = (const float*)d_in[9];
    const float* bond_emb   = (const float*)d_in[10];
    const float* lin_w      = (const float*)d_in[11];
    const float* lin_b      = (const float*)d_in[12];
    float* out = (float*)d_out;

    unsigned* pack = (unsigned*)d_ws;                      // 8 MB
    unsigned short* bftp = (unsigned short*)((char*)d_ws + (size_t)PACK_DWORDS * 4);

    // Kernel 0: repack tables (+ B-fragment table); ws re-poisoned each call
    pack_kernel<<<dim3(ATOM_VOC, ATOM_VOC), dim3(128), 0, stream>>>(
        apw, apb, means, stds, lin_w, pack, bftp, 1);

    // Output 1: atoms_emb [L, B, D] at offset 0
    {
        const int total = NL * NB * (D_MODEL / 4);
        atoms_emb_kernel<<<dim3((total + 255) / 256), dim3(256), 0, stream>>>(
            atoms, chirals, atype_emb, chiral_emb, out);
    }
    // Output 2: ap [B, NHEAD, L, L] at offset L*B*D
    {
        float* out2 = out + (size_t)NL * NB * D_MODEL;
        ap_kernel<<<dim3(NL, NB), dim3(512), 0, stream>>>(
            atoms, coords, bonds, pack, bftp, bond_emb, lin_b, out2);
    }
}